// Round 1
// baseline (172.243 us; speedup 1.0000x reference)
//
#include <hip/hip_runtime.h>

// VQ quantizer: z [8,8,16,64,64] f32, codebook [512,8] f32
// outputs concat: z_q_st (4194304 f32) | vq_loss (1 f32) | idx (524288 f32-valued)

#define NPTS      524288      // 8*16*64*64
#define KCODES    512
#define DDIM      8
#define CH_STRIDE 65536       // T*H*W
#define B_STRIDE  524288      // D*T*H*W

// numpy pairwise-sum tree for n=8 (pairwise_sum unrolled-8 path):
// ((x0+x1)+(x2+x3)) + ((x4+x5)+(x6+x7)), products rounded separately (no fma).
__device__ __forceinline__ float np_sumsq8(const float* x) {
    float p0 = __fmul_rn(x[0], x[0]);
    float p1 = __fmul_rn(x[1], x[1]);
    float p2 = __fmul_rn(x[2], x[2]);
    float p3 = __fmul_rn(x[3], x[3]);
    float p4 = __fmul_rn(x[4], x[4]);
    float p5 = __fmul_rn(x[5], x[5]);
    float p6 = __fmul_rn(x[6], x[6]);
    float p7 = __fmul_rn(x[7], x[7]);
    return __fadd_rn(__fadd_rn(__fadd_rn(p0, p1), __fadd_rn(p2, p3)),
                     __fadd_rn(__fadd_rn(p4, p5), __fadd_rn(p6, p7)));
}

__global__ void e2_precompute(const float* __restrict__ cb, float* __restrict__ e2) {
    int k = blockIdx.x * blockDim.x + threadIdx.x;
    if (k >= KCODES) return;
    float c[DDIM];
    #pragma unroll
    for (int j = 0; j < DDIM; ++j) c[j] = cb[k * DDIM + j];
    e2[k] = np_sumsq8(c);
}

__global__ __launch_bounds__(256) void vq_main(
    const float* __restrict__ z, const float* __restrict__ cb,
    const float* __restrict__ e2, float* __restrict__ out_zq,
    float* __restrict__ out_loss, float* __restrict__ out_idx)
{
    const int n = blockIdx.x * 256 + threadIdx.x;
    const int b = n >> 16;        // batch
    const int s = n & 65535;      // spatial offset within batch
    const float* zp = z + (size_t)b * B_STRIDE + s;

    float zv[DDIM];
    #pragma unroll
    for (int j = 0; j < DDIM; ++j) zv[j] = zp[(size_t)j * CH_STRIDE];

    const float z2 = np_sumsq8(zv);

    float dmin = 3.402823466e+38f;
    int imin = 0;
    for (int k = 0; k < KCODES; ++k) {
        const float* c = cb + k * DDIM;   // k-uniform address -> scalar loads
        // OpenBLAS sgemm K-loop: sequential ascending-k fma chain from 0
        float ze = 0.0f;
        #pragma unroll
        for (int j = 0; j < DDIM; ++j) ze = __fmaf_rn(zv[j], c[j], ze);
        float t = __fadd_rn(z2, e2[k]);          // np: (z2 + e2)
        float dist = __fmaf_rn(-2.0f, ze, t);    // np: t - (2*ze); 2*ze exact
        if (dist < dmin) { dmin = dist; imin = k; }   // np first-min tie-break
    }

    out_idx[n] = (float)imin;

    const float* cw = cb + imin * DDIM;
    float* op = out_zq + (size_t)b * B_STRIDE + s;
    float lsum = 0.0f;
    #pragma unroll
    for (int j = 0; j < DDIM; ++j) {
        float zq = cw[j];
        float t  = __fsub_rn(zq, zv[j]);            // np: z_q - z
        op[(size_t)j * CH_STRIDE] = __fadd_rn(zv[j], t);  // np: z + (z_q - z)
        lsum = __fmaf_rn(t, t, lsum);               // loss: accuracy-only (2% tol)
    }

    // block reduction of loss partials: wave shuffle -> LDS -> one atomic/block
    #pragma unroll
    for (int off = 32; off > 0; off >>= 1) lsum += __shfl_down(lsum, off, 64);
    __shared__ float wsum[4];
    const int lane = threadIdx.x & 63;
    const int wid  = threadIdx.x >> 6;
    if (lane == 0) wsum[wid] = lsum;
    __syncthreads();
    if (threadIdx.x == 0) {
        float bs = ((wsum[0] + wsum[1]) + (wsum[2] + wsum[3]));
        // vq_loss = codebk + BETA*commit = (1 + 0.25) * mean((z_q - z)^2)
        atomicAdd(out_loss, bs * (1.25f / 4194304.0f));
    }
}

extern "C" void kernel_launch(void* const* d_in, const int* in_sizes, int n_in,
                              void* d_out, int out_size, void* d_ws, size_t ws_size,
                              hipStream_t stream) {
    const float* z  = (const float*)d_in[0];
    const float* cb = (const float*)d_in[1];
    float* out      = (float*)d_out;
    float* out_zq   = out;                    // 4194304 elems
    float* out_loss = out + 4194304;          // 1 elem
    float* out_idx  = out + 4194305;          // 524288 elems (as float values)
    float* e2       = (float*)d_ws;           // 512 floats scratch

    hipMemsetAsync(out_loss, 0, sizeof(float), stream);
    e2_precompute<<<2, 256, 0, stream>>>(cb, e2);
    vq_main<<<NPTS / 256, 256, 0, stream>>>(z, cb, e2, out_zq, out_loss, out_idx);
}